// Round 6
// baseline (948.925 us; speedup 1.0000x reference)
//
#include <hip/hip_runtime.h>

#define NN 100000
#define NE 1600000
#define CH 64
#define STEPS 10
#define ALPHA 0.1f

#define SCAN_BLK 256
#define SCAN_ITEMS 4
#define SCAN_TILE (SCAN_BLK * SCAN_ITEMS)   // 1024
#define N_TILES ((NN + SCAN_TILE - 1) / SCAN_TILE)  // 98

typedef unsigned int uint;
typedef unsigned long long ull;

// pack two f32 into bf16x2 word, round-to-nearest-even
__device__ inline uint pack_bf16x2(float x, float y) {
    uint ux = __float_as_uint(x);
    ux += 0x7FFFu + ((ux >> 16) & 1u);
    uint uy = __float_as_uint(y);
    uy += 0x7FFFu + ((uy >> 16) & 1u);
    return (ux >> 16) | (uy & 0xFFFF0000u);
}

// ---- histogram of dst ----
__global__ void k_count(const int* __restrict__ dst, int* __restrict__ cnt, int E) {
    int e = blockIdx.x * blockDim.x + threadIdx.x;
    if (e < E) atomicAdd(&cnt[dst[e]], 1);
}

// ---- dinv = rsqrt(max(deg,1)) ----
__global__ void k_dinv(const int* __restrict__ cnt, float* __restrict__ dinv, int n) {
    int i = blockIdx.x * blockDim.x + threadIdx.x;
    if (i < n) dinv[i] = rsqrtf(fmaxf((float)cnt[i], 1.0f));
}

// ---- scan phase 1: per-tile sums ----
__global__ void k_scan1(const int* __restrict__ cnt, int* __restrict__ tileSums, int n) {
    __shared__ int lds[SCAN_BLK];
    int base = blockIdx.x * SCAN_TILE + threadIdx.x * SCAN_ITEMS;
    int s = 0;
    #pragma unroll
    for (int j = 0; j < SCAN_ITEMS; ++j) { int i = base + j; if (i < n) s += cnt[i]; }
    lds[threadIdx.x] = s;
    __syncthreads();
    for (int off = SCAN_BLK / 2; off > 0; off >>= 1) {
        if (threadIdx.x < off) lds[threadIdx.x] += lds[threadIdx.x + off];
        __syncthreads();
    }
    if (threadIdx.x == 0) tileSums[blockIdx.x] = lds[0];
}

// ---- scan phase 2: exclusive scan of tile sums ----
__global__ void k_scan2(int* __restrict__ tileSums, int nTiles) {
    __shared__ int lds[256];
    int v = (threadIdx.x < nTiles) ? tileSums[threadIdx.x] : 0;
    lds[threadIdx.x] = v;
    __syncthreads();
    for (int off = 1; off < 256; off <<= 1) {
        int t = (threadIdx.x >= off) ? lds[threadIdx.x - off] : 0;
        __syncthreads();
        lds[threadIdx.x] += t;
        __syncthreads();
    }
    if (threadIdx.x < nTiles) tileSums[threadIdx.x] = lds[threadIdx.x] - v;
}

// ---- scan phase 3: per-tile exclusive scan + tile offset -> rowptr & cursor ----
__global__ void k_scan3(const int* __restrict__ cnt, const int* __restrict__ tileOffs,
                        int* __restrict__ rowptr, int* __restrict__ cursor, int n) {
    __shared__ int lds[SCAN_BLK];
    int base = blockIdx.x * SCAN_TILE + threadIdx.x * SCAN_ITEMS;
    int vals[SCAN_ITEMS];
    int s = 0;
    #pragma unroll
    for (int j = 0; j < SCAN_ITEMS; ++j) {
        int i = base + j;
        vals[j] = (i < n) ? cnt[i] : 0;
        s += vals[j];
    }
    lds[threadIdx.x] = s;
    __syncthreads();
    int inc = s;
    for (int off = 1; off < SCAN_BLK; off <<= 1) {
        int t = (threadIdx.x >= off) ? lds[threadIdx.x - off] : 0;
        __syncthreads();
        lds[threadIdx.x] += t;
        __syncthreads();
    }
    int excl = lds[threadIdx.x] - inc + tileOffs[blockIdx.x];
    #pragma unroll
    for (int j = 0; j < SCAN_ITEMS; ++j) {
        int i = base + j;
        if (i < n) { rowptr[i] = excl; cursor[i] = excl; excl += vals[j]; }
    }
    if (blockIdx.x == 0 && threadIdx.x == 0) rowptr[n] = NE;
}

// ---- scatter edges into CSR order (by dst); single packed 8B write per edge ----
__global__ void k_fill(const int* __restrict__ src, const int* __restrict__ dst,
                       const float* __restrict__ dinv, int* __restrict__ cursor,
                       int2* __restrict__ pair, int E) {
    int e = blockIdx.x * blockDim.x + threadIdx.x;
    if (e < E) {
        int s = src[e], d = dst[e];
        int pos = atomicAdd(&cursor[d], 1);
        pair[pos] = make_int2(s, __float_as_int(dinv[s] * dinv[d]));
    }
}

// ---- propagation: one wave per node; 2 edges per wave-load (one per 32-lane half).
//      Straight-line predicated batch of 16 dual-loads => up to 16 gathers in
//      flight per wave (deg<=32 fully covered; rare tail loop beyond).
//      Intermediate h is bf16x2; acc stays f32. ----
template<bool SRCF32, bool INIT, bool WRITEHN, bool FINAL>
__global__ __launch_bounds__(256) void
k_prop(const int* __restrict__ rowptr, const int2* __restrict__ pair,
       const void* __restrict__ h, uint* __restrict__ hn,
       float* __restrict__ acc, const float* __restrict__ x) {
    int wid  = (int)((blockIdx.x * (long long)blockDim.x + threadIdx.x) >> 6);
    int lane = threadIdx.x & 63;
    if (wid >= NN) return;
    int half = lane >> 5;       // which edge of the dual
    int cl   = lane & 31;       // channel-pair index
    int start = rowptr[wid];
    int end   = rowptr[wid + 1];
    int safe  = start < NE ? start : NE - 1;   // valid clamp addr for inactive slots
    const ull* pp = (const ull*)pair;

    float ax = 0.0f, ay = 0.0f;

    // ---- main straight-line batch: 16 duals = up to 32 edges ----
    {
        ull c[16];
        #pragma unroll
        for (int j = 0; j < 16; ++j) {
            int ix = start + 2 * j + half;
            c[j] = __builtin_nontemporal_load(pp + (ix < end ? ix : safe));
        }
        if (SRCF32) {
            float2 hv[16];
            #pragma unroll
            for (int j = 0; j < 16; ++j) {
                int s = (int)(uint)c[j];
                hv[j] = ((const float2*)((const float*)h + (long long)s * CH))[cl];
            }
            #pragma unroll
            for (int j = 0; j < 16; ++j) {
                int ix = start + 2 * j + half;
                float wt = (ix < end) ? __uint_as_float((uint)(c[j] >> 32)) : 0.0f;
                ax = fmaf(hv[j].x, wt, ax);
                ay = fmaf(hv[j].y, wt, ay);
            }
        } else {
            uint v[16];
            #pragma unroll
            for (int j = 0; j < 16; ++j) {
                int s = (int)(uint)c[j];
                v[j] = ((const uint*)h)[(long long)s * (CH / 2) + cl];
            }
            #pragma unroll
            for (int j = 0; j < 16; ++j) {
                int ix = start + 2 * j + half;
                float wt = (ix < end) ? __uint_as_float((uint)(c[j] >> 32)) : 0.0f;
                ax = fmaf(__uint_as_float(v[j] << 16), wt, ax);
                ay = fmaf(__uint_as_float(v[j] & 0xFFFF0000u), wt, ay);
            }
        }
    }

    // ---- rare tail: deg > 32 ----
    for (int p = start + 32; p < end; p += 2) {
        int ix = p + half;
        if (ix < end) {
            ull c = pp[ix];
            int s = (int)(uint)c;
            float wt = __uint_as_float((uint)(c >> 32));
            if (SRCF32) {
                float2 hv = ((const float2*)((const float*)h + (long long)s * CH))[cl];
                ax = fmaf(hv.x, wt, ax); ay = fmaf(hv.y, wt, ay);
            } else {
                uint v = ((const uint*)h)[(long long)s * (CH / 2) + cl];
                ax = fmaf(__uint_as_float(v << 16), wt, ax);
                ay = fmaf(__uint_as_float(v & 0xFFFF0000u), wt, ay);
            }
        }
    }

    ax += __shfl_xor(ax, 32);
    ay += __shfl_xor(ay, 32);
    if (half == 0) {
        long long o = (long long)wid * (CH / 2) + cl;
        if (WRITEHN) hn[o] = pack_bf16x2(ax, ay);
        if (INIT) {
            ((float2*)acc)[o] = make_float2(ax, ay);
        } else if (FINAL) {
            float2 t = ((float2*)acc)[o];
            t.x += ax; t.y += ay;
            float2 xv = ((const float2*)x)[o];
            float2 r;
            r.x = ALPHA * xv.x + (1.0f - ALPHA) * (t.x * (1.0f / STEPS));
            r.y = ALPHA * xv.y + (1.0f - ALPHA) * (t.y * (1.0f / STEPS));
            ((float2*)acc)[o] = r;
        } else {
            float2 t = ((float2*)acc)[o];
            t.x += ax; t.y += ay;
            ((float2*)acc)[o] = t;
        }
    }
}

extern "C" void kernel_launch(void* const* d_in, const int* in_sizes, int n_in,
                              void* d_out, int out_size, void* d_ws, size_t ws_size,
                              hipStream_t stream) {
    const float* x  = (const float*)d_in[0];
    const int*   ei = (const int*)d_in[1];     // [2, NE]: row0=src, row1=dst
    const int*   src = ei;
    const int*   dst = ei + NE;
    float* out = (float*)d_out;                // doubles as f32 acc

    char* ws = (char*)d_ws;
    const size_t MB = 1024 * 1024;
    int*   cnt      = (int*)  (ws);                 // 400 KB
    float* dinv     = (float*)(ws + 1 * MB);        // 400 KB
    int*   rowptr   = (int*)  (ws + 2 * MB);        // 400 KB (+1)
    int*   cursor   = (int*)  (ws + 3 * MB);        // 400 KB
    int*   tileSums = (int*)  (ws + 4 * MB);        // <1 KB
    int2*  pair     = (int2*) (ws + 5 * MB);        // 12.8 MB
    uint*  hA       = (uint*) (ws + 19 * MB);       // 12.8 MB (bf16x2)
    uint*  hB       = (uint*) (ws + 33 * MB);       // 12.8 MB (total ~46 MB)

    hipMemsetAsync(cnt, 0, NN * sizeof(int), stream);
    k_count<<<(NE + 255) / 256, 256, 0, stream>>>(dst, cnt, NE);
    k_dinv <<<(NN + 255) / 256, 256, 0, stream>>>(cnt, dinv, NN);
    k_scan1<<<N_TILES, SCAN_BLK, 0, stream>>>(cnt, tileSums, NN);
    k_scan2<<<1, 256, 0, stream>>>(tileSums, N_TILES);
    k_scan3<<<N_TILES, SCAN_BLK, 0, stream>>>(cnt, tileSums, rowptr, cursor, NN);
    k_fill <<<(NE + 255) / 256, 256, 0, stream>>>(src, dst, dinv, cursor, pair, NE);

    const int propBlocks = (NN * 64 + 255) / 256;   // one wave per node
    uint* bufs[2] = {hA, hB};
    const void* hcur = (const void*)x;
    for (int t = 0; t < STEPS; ++t) {
        uint* hn = bufs[t & 1];
        if (t == 0)
            k_prop<true,  true,  true,  false><<<propBlocks, 256, 0, stream>>>(rowptr, pair, hcur, hn, out, x);
        else if (t == STEPS - 1)
            k_prop<false, false, false, true ><<<propBlocks, 256, 0, stream>>>(rowptr, pair, hcur, hn, out, x);
        else
            k_prop<false, false, true,  false><<<propBlocks, 256, 0, stream>>>(rowptr, pair, hcur, hn, out, x);
        hcur = (const void*)hn;
    }
}

// Round 7
// 576.408 us; speedup vs baseline: 1.6463x; 1.6463x over previous
//
#include <hip/hip_runtime.h>

#define NN 100000
#define NE 1600000
#define CH 64
#define STEPS 10
#define ALPHA 0.1f

#define SCAN_BLK 256
#define SCAN_ITEMS 4
#define SCAN_TILE (SCAN_BLK * SCAN_ITEMS)   // 1024
#define N_TILES ((NN + SCAN_TILE - 1) / SCAN_TILE)  // 98

typedef unsigned int uint;
typedef unsigned long long ull;

// pack two f32 into bf16x2 word, round-to-nearest-even (low = first arg)
__device__ inline uint pack_bf16x2(float x, float y) {
    uint ux = __float_as_uint(x);
    ux += 0x7FFFu + ((ux >> 16) & 1u);
    uint uy = __float_as_uint(y);
    uy += 0x7FFFu + ((uy >> 16) & 1u);
    return (ux >> 16) | (uy & 0xFFFF0000u);
}

// ---- histogram of dst ----
__global__ void k_count(const int* __restrict__ dst, int* __restrict__ cnt, int E) {
    int e = blockIdx.x * blockDim.x + threadIdx.x;
    if (e < E) atomicAdd(&cnt[dst[e]], 1);
}

// ---- dinv = rsqrt(max(deg,1)) ----
__global__ void k_dinv(const int* __restrict__ cnt, float* __restrict__ dinv, int n) {
    int i = blockIdx.x * blockDim.x + threadIdx.x;
    if (i < n) dinv[i] = rsqrtf(fmaxf((float)cnt[i], 1.0f));
}

// ---- scan phase 1: per-tile sums ----
__global__ void k_scan1(const int* __restrict__ cnt, int* __restrict__ tileSums, int n) {
    __shared__ int lds[SCAN_BLK];
    int base = blockIdx.x * SCAN_TILE + threadIdx.x * SCAN_ITEMS;
    int s = 0;
    #pragma unroll
    for (int j = 0; j < SCAN_ITEMS; ++j) { int i = base + j; if (i < n) s += cnt[i]; }
    lds[threadIdx.x] = s;
    __syncthreads();
    for (int off = SCAN_BLK / 2; off > 0; off >>= 1) {
        if (threadIdx.x < off) lds[threadIdx.x] += lds[threadIdx.x + off];
        __syncthreads();
    }
    if (threadIdx.x == 0) tileSums[blockIdx.x] = lds[0];
}

// ---- scan phase 2: exclusive scan of tile sums ----
__global__ void k_scan2(int* __restrict__ tileSums, int nTiles) {
    __shared__ int lds[256];
    int v = (threadIdx.x < nTiles) ? tileSums[threadIdx.x] : 0;
    lds[threadIdx.x] = v;
    __syncthreads();
    for (int off = 1; off < 256; off <<= 1) {
        int t = (threadIdx.x >= off) ? lds[threadIdx.x - off] : 0;
        __syncthreads();
        lds[threadIdx.x] += t;
        __syncthreads();
    }
    if (threadIdx.x < nTiles) tileSums[threadIdx.x] = lds[threadIdx.x] - v;
}

// ---- scan phase 3: per-tile exclusive scan + tile offset -> rowptr & cursor ----
__global__ void k_scan3(const int* __restrict__ cnt, const int* __restrict__ tileOffs,
                        int* __restrict__ rowptr, int* __restrict__ cursor, int n) {
    __shared__ int lds[SCAN_BLK];
    int base = blockIdx.x * SCAN_TILE + threadIdx.x * SCAN_ITEMS;
    int vals[SCAN_ITEMS];
    int s = 0;
    #pragma unroll
    for (int j = 0; j < SCAN_ITEMS; ++j) {
        int i = base + j;
        vals[j] = (i < n) ? cnt[i] : 0;
        s += vals[j];
    }
    lds[threadIdx.x] = s;
    __syncthreads();
    int inc = s;
    for (int off = 1; off < SCAN_BLK; off <<= 1) {
        int t = (threadIdx.x >= off) ? lds[threadIdx.x - off] : 0;
        __syncthreads();
        lds[threadIdx.x] += t;
        __syncthreads();
    }
    int excl = lds[threadIdx.x] - inc + tileOffs[blockIdx.x];
    #pragma unroll
    for (int j = 0; j < SCAN_ITEMS; ++j) {
        int i = base + j;
        if (i < n) { rowptr[i] = excl; cursor[i] = excl; excl += vals[j]; }
    }
    if (blockIdx.x == 0 && threadIdx.x == 0) rowptr[n] = NE;
}

// ---- scatter edges into CSR order (by dst); single packed 8B write per edge ----
__global__ void k_fill(const int* __restrict__ src, const int* __restrict__ dst,
                       const float* __restrict__ dinv, int* __restrict__ cursor,
                       int2* __restrict__ pair, int E) {
    int e = blockIdx.x * blockDim.x + threadIdx.x;
    if (e < E) {
        int s = src[e], d = dst[e];
        int pos = atomicAdd(&cursor[d], 1);
        pair[pos] = make_int2(s, __float_as_int(dinv[s] * dinv[d]));
    }
}

// ---- propagation: one wave per node; quarter-split: q=lane>>4 owns edge slot,
//      cl=lane&15 owns a 4-channel group (uint2 of bf16 / float4 of f32).
//      One gather instruction covers 4 edges. Batch: 16 edges always + 8
//      predicated + rare loop. ACCMODE: 0 none(deferred) 1 init 2 add 3 final ----
template<bool SRCF32, bool WRITEHN, int ACCMODE>
__global__ __launch_bounds__(256) void
k_prop(const int* __restrict__ rowptr, const int2* __restrict__ pair,
       const void* __restrict__ h, uint2* __restrict__ hn,
       float* __restrict__ acc, const float* __restrict__ x) {
    int wid  = (int)((blockIdx.x * (long long)blockDim.x + threadIdx.x) >> 6);
    int lane = threadIdx.x & 63;
    if (wid >= NN) return;
    int q  = lane >> 4;        // edge slot within a quad
    int cl = lane & 15;        // 4-channel group index
    int start = rowptr[wid];
    int end   = rowptr[wid + 1];
    int safe  = start < NE ? start : NE - 1;
    const ull* pp = (const ull*)pair;

    float a0 = 0.f, a1 = 0.f, a2 = 0.f, a3 = 0.f;

    #define GATHER_FMA(PE, ACTIVE)                                               \
        {                                                                        \
            int   s_ = (int)(uint)(PE);                                          \
            float wt = (ACTIVE) ? __uint_as_float((uint)((PE) >> 32)) : 0.0f;    \
            if (SRCF32) {                                                        \
                float4 hv = ((const float4*)h)[(long long)s_ * 16 + cl];         \
                a0 = fmaf(hv.x, wt, a0); a1 = fmaf(hv.y, wt, a1);                \
                a2 = fmaf(hv.z, wt, a2); a3 = fmaf(hv.w, wt, a3);                \
            } else {                                                             \
                uint2 hv = ((const uint2*)h)[(long long)s_ * 16 + cl];           \
                a0 = fmaf(__uint_as_float(hv.x << 16),        wt, a0);           \
                a1 = fmaf(__uint_as_float(hv.x & 0xFFFF0000u), wt, a1);          \
                a2 = fmaf(__uint_as_float(hv.y << 16),        wt, a2);           \
                a3 = fmaf(__uint_as_float(hv.y & 0xFFFF0000u), wt, a3);          \
            }                                                                    \
        }

    // ---- batch 1: 16 edges (4 quad-slots), always ----
    {
        ull pe[4];
        #pragma unroll
        for (int j = 0; j < 4; ++j) {
            int ix = start + 4 * j + q;
            pe[j] = pp[ix < end ? ix : safe];
        }
        #pragma unroll
        for (int j = 0; j < 4; ++j) {
            int ix = start + 4 * j + q;
            GATHER_FMA(pe[j], ix < end);
        }
    }
    // ---- batch 2: 8 more edges if deg > 16 (covers deg <= 24, ~98%) ----
    if (end > start + 16) {
        ull pe[2];
        #pragma unroll
        for (int j = 0; j < 2; ++j) {
            int ix = start + 16 + 4 * j + q;
            pe[j] = pp[ix < end ? ix : safe];
        }
        #pragma unroll
        for (int j = 0; j < 2; ++j) {
            int ix = start + 16 + 4 * j + q;
            GATHER_FMA(pe[j], ix < end);
        }
    }
    // ---- rare tail: deg > 24 ----
    for (int p = start + 24; p < end; p += 4) {
        int ix = p + q;
        if (ix < end) {
            ull pe = pp[ix];
            GATHER_FMA(pe, true);
        }
    }
    #undef GATHER_FMA

    // reduce across the 4 quad-slots
    a0 += __shfl_xor(a0, 16); a1 += __shfl_xor(a1, 16);
    a2 += __shfl_xor(a2, 16); a3 += __shfl_xor(a3, 16);
    a0 += __shfl_xor(a0, 32); a1 += __shfl_xor(a1, 32);
    a2 += __shfl_xor(a2, 32); a3 += __shfl_xor(a3, 32);

    if (q == 0) {
        long long o = (long long)wid * 16 + cl;
        if (WRITEHN) hn[o] = make_uint2(pack_bf16x2(a0, a1), pack_bf16x2(a2, a3));
        if (ACCMODE == 1) {
            ((float4*)acc)[o] = make_float4(a0, a1, a2, a3);
        } else if (ACCMODE == 2) {
            float4 t = ((float4*)acc)[o];
            t.x += a0; t.y += a1; t.z += a2; t.w += a3;
            ((float4*)acc)[o] = t;
        } else if (ACCMODE == 3) {
            float4 t = ((float4*)acc)[o];
            float4 xv = ((const float4*)x)[o];
            float4 r;
            r.x = ALPHA * xv.x + (1.0f - ALPHA) * ((t.x + a0) * (1.0f / STEPS));
            r.y = ALPHA * xv.y + (1.0f - ALPHA) * ((t.y + a1) * (1.0f / STEPS));
            r.z = ALPHA * xv.z + (1.0f - ALPHA) * ((t.z + a2) * (1.0f / STEPS));
            r.w = ALPHA * xv.w + (1.0f - ALPHA) * ((t.w + a3) * (1.0f / STEPS));
            ((float4*)acc)[o] = r;
        }
    }
}

// ---- deferred combine: out = alpha*x + (1-alpha)/STEPS * sum_t h_t ----
__global__ void k_sum10(const uint2* __restrict__ hbase, const float* __restrict__ x,
                        float* __restrict__ out, int total) {
    int i = blockIdx.x * blockDim.x + threadIdx.x;
    if (i >= total) return;
    float s0 = 0.f, s1 = 0.f, s2 = 0.f, s3 = 0.f;
    #pragma unroll
    for (int t = 0; t < STEPS; ++t) {
        uint2 v = hbase[(size_t)t * (NN * 16) + i];
        s0 += __uint_as_float(v.x << 16);
        s1 += __uint_as_float(v.x & 0xFFFF0000u);
        s2 += __uint_as_float(v.y << 16);
        s3 += __uint_as_float(v.y & 0xFFFF0000u);
    }
    float4 xv = ((const float4*)x)[i];
    float4 r;
    r.x = ALPHA * xv.x + (1.0f - ALPHA) * (s0 * (1.0f / STEPS));
    r.y = ALPHA * xv.y + (1.0f - ALPHA) * (s1 * (1.0f / STEPS));
    r.z = ALPHA * xv.z + (1.0f - ALPHA) * (s2 * (1.0f / STEPS));
    r.w = ALPHA * xv.w + (1.0f - ALPHA) * (s3 * (1.0f / STEPS));
    ((float4*)out)[i] = r;
}

extern "C" void kernel_launch(void* const* d_in, const int* in_sizes, int n_in,
                              void* d_out, int out_size, void* d_ws, size_t ws_size,
                              hipStream_t stream) {
    const float* x  = (const float*)d_in[0];
    const int*   ei = (const int*)d_in[1];     // [2, NE]: row0=src, row1=dst
    const int*   src = ei;
    const int*   dst = ei + NE;
    float* out = (float*)d_out;

    char* ws = (char*)d_ws;
    const size_t MB = 1024 * 1024;
    int*   cnt      = (int*)  (ws);                 // 400 KB
    float* dinv     = (float*)(ws + 1 * MB);        // 400 KB
    int*   rowptr   = (int*)  (ws + 2 * MB);        // 400 KB (+1)
    int*   cursor   = (int*)  (ws + 3 * MB);        // 400 KB
    int*   tileSums = (int*)  (ws + 4 * MB);        // <1 KB
    int2*  pair     = (int2*) (ws + 5 * MB);        // 12.8 MB
    uint2* hbase    = (uint2*)(ws + 20 * MB);       // up to 10 x 12.8 MB

    const size_t HBUF = (size_t)NN * 16;            // uint2 per buffer (12.8 MB)
    const bool defer = ws_size >= (size_t)(20) * MB + 10 * HBUF * sizeof(uint2) + MB;

    hipMemsetAsync(cnt, 0, NN * sizeof(int), stream);
    k_count<<<(NE + 255) / 256, 256, 0, stream>>>(dst, cnt, NE);
    k_dinv <<<(NN + 255) / 256, 256, 0, stream>>>(cnt, dinv, NN);
    k_scan1<<<N_TILES, SCAN_BLK, 0, stream>>>(cnt, tileSums, NN);
    k_scan2<<<1, 256, 0, stream>>>(tileSums, N_TILES);
    k_scan3<<<N_TILES, SCAN_BLK, 0, stream>>>(cnt, tileSums, rowptr, cursor, NN);
    k_fill <<<(NE + 255) / 256, 256, 0, stream>>>(src, dst, dinv, cursor, pair, NE);

    const int propBlocks = (NN * 64 + 255) / 256;   // one wave per node

    if (defer) {
        // props write h_t only; one final pass sums all 10
        const void* hcur = (const void*)x;
        for (int t = 0; t < STEPS; ++t) {
            uint2* hn = hbase + (size_t)t * HBUF;
            if (t == 0)
                k_prop<true,  true, 0><<<propBlocks, 256, 0, stream>>>(rowptr, pair, hcur, hn, out, x);
            else
                k_prop<false, true, 0><<<propBlocks, 256, 0, stream>>>(rowptr, pair, hcur, hn, out, x);
            hcur = (const void*)hn;
        }
        const int total = NN * 16;
        k_sum10<<<(total + 255) / 256, 256, 0, stream>>>(hbase, x, out, total);
    } else {
        // fallback: ping-pong h + f32 acc in out
        uint2* hA = hbase;
        uint2* hB = hbase + HBUF;
        uint2* bufs[2] = {hA, hB};
        const void* hcur = (const void*)x;
        for (int t = 0; t < STEPS; ++t) {
            uint2* hn = bufs[t & 1];
            if (t == 0)
                k_prop<true,  true,  1><<<propBlocks, 256, 0, stream>>>(rowptr, pair, hcur, hn, out, x);
            else if (t == STEPS - 1)
                k_prop<false, false, 3><<<propBlocks, 256, 0, stream>>>(rowptr, pair, hcur, hn, out, x);
            else
                k_prop<false, true,  2><<<propBlocks, 256, 0, stream>>>(rowptr, pair, hcur, hn, out, x);
            hcur = (const void*)hn;
        }
    }
}